// Round 2
// baseline (1274.372 us; speedup 1.0000x reference)
//
#include <hip/hip_runtime.h>
#include <hip/hip_bf16.h>
#include <math.h>

// B=2, S=2048, H=4096, NH=32, NKV=8, HD=128, Q_SIZE=4096, KV_SIZE=1024, N_qkv=6144
// All float inputs/outputs are fp32 (per reference); compute pipeline is bf16 MFMA + fp32 acc.

typedef __attribute__((ext_vector_type(8))) __bf16 bf16x8;
typedef __attribute__((ext_vector_type(4))) float floatx4;

__device__ __forceinline__ floatx4 mfma16(bf16x8 a, bf16x8 b, floatx4 c) {
    return __builtin_amdgcn_mfma_f32_16x16x32_bf16(a, b, c, 0, 0, 0);
}

// ---------------------------------------------------------------------------
// fp32 -> bf16 elementwise convert. n % 1024 == 0. Each thread: 4 elems.
// ---------------------------------------------------------------------------
__global__ __launch_bounds__(256)
void convert_kernel(const float* __restrict__ in, __hip_bfloat16* __restrict__ out,
                    int n) {
    int i = (blockIdx.x * 256 + threadIdx.x) * 4;
    if (i >= n) return;
    float4 v = *(const float4*)(in + i);
    union { __hip_bfloat16 h[4]; uint2 u; } pk;
    pk.h[0] = __float2bfloat16(v.x);
    pk.h[1] = __float2bfloat16(v.y);
    pk.h[2] = __float2bfloat16(v.z);
    pk.h[3] = __float2bfloat16(v.w);
    *(uint2*)(out + i) = pk.u;
}

// ---------------------------------------------------------------------------
// fp32 in[r][c] -> bf16 out[c][r] transpose (weights). R%64==0, C%64==0.
// grid = (C/64, R/64), block = 256.
// ---------------------------------------------------------------------------
__global__ __launch_bounds__(256)
void transpose_f32_bf16_kernel(const float* __restrict__ in,
                               __hip_bfloat16* __restrict__ out, int R, int C) {
    __shared__ __hip_bfloat16 tile[64][65];
    const int r0 = blockIdx.y * 64, c0 = blockIdx.x * 64;
    const int t = threadIdx.x;
    #pragma unroll
    for (int i = 0; i < 16; ++i) {
        int idx = t + 256 * i;
        int rl = idx >> 6, cl = idx & 63;
        tile[rl][cl] = __float2bfloat16(in[(size_t)(r0 + rl) * C + (c0 + cl)]);
    }
    __syncthreads();
    #pragma unroll
    for (int i = 0; i < 16; ++i) {
        int idx = t + 256 * i;
        int cl = idx >> 6, rl = idx & 63;
        out[(size_t)(c0 + cl) * R + (r0 + rl)] = tile[rl][cl];
    }
}

// ---------------------------------------------------------------------------
// bf16 batched transpose: in[b][r][c] -> out[b][c][r].
// ---------------------------------------------------------------------------
__global__ __launch_bounds__(256)
void transpose_bf16_kernel(const __hip_bfloat16* __restrict__ in,
                           __hip_bfloat16* __restrict__ out, int R, int C) {
    __shared__ __hip_bfloat16 tile[64][65];
    const int bz = blockIdx.z;
    const __hip_bfloat16* inb  = in  + (size_t)bz * R * C;
    __hip_bfloat16*       outb = out + (size_t)bz * R * C;
    const int r0 = blockIdx.y * 64, c0 = blockIdx.x * 64;
    const int t = threadIdx.x;
    #pragma unroll
    for (int i = 0; i < 16; ++i) {
        int idx = t + 256 * i;
        int rl = idx >> 6, cl = idx & 63;
        tile[rl][cl] = inb[(size_t)(r0 + rl) * C + (c0 + cl)];
    }
    __syncthreads();
    #pragma unroll
    for (int i = 0; i < 16; ++i) {
        int idx = t + 256 * i;
        int cl = idx >> 6, rl = idx & 63;
        outb[(size_t)(c0 + cl) * R + (r0 + rl)] = tile[rl][cl];
    }
}

// ---------------------------------------------------------------------------
// bf16 GEMM: C[M,N] = A[M,K] * Bt[N,K]^T.  128x128 tile, BK=32, 4 waves.
// MODE 0: fp32 store to Cp (row-major, ld=N).
// MODE 1: QKV scatter -> Qr[b][h][s][d], Kr[b][kv][s][d], Vv[b][kv][s][d] (bf16)
// ---------------------------------------------------------------------------
template <int MODE>
__global__ __launch_bounds__(256)
void gemm_bt_kernel(const __hip_bfloat16* __restrict__ A,
                    const __hip_bfloat16* __restrict__ Bt,
                    float* __restrict__ Cp,
                    __hip_bfloat16* __restrict__ Qr,
                    __hip_bfloat16* __restrict__ Kr,
                    __hip_bfloat16* __restrict__ Vv,
                    int M, int N, int K) {
    __shared__ __align__(16) __hip_bfloat16 As[128 * 32];
    __shared__ __align__(16) __hip_bfloat16 Bs[128 * 32];

    const int m0 = blockIdx.y * 128, n0 = blockIdx.x * 128;
    const int tid  = threadIdx.x;
    const int wave = tid >> 6, lane = tid & 63;
    const int quad = lane >> 4, l16 = lane & 15;
    const int wm = (wave >> 1) * 64, wn = (wave & 1) * 64;

    floatx4 acc[4][4] = {};

    for (int kt = 0; kt < K; kt += 32) {
        #pragma unroll
        for (int i = 0; i < 2; ++i) {
            int idx = tid + 256 * i;
            int row = idx >> 2;
            int kc  = (idx & 3) << 3;
            *(uint4*)(&As[row * 32 + kc]) =
                *(const uint4*)(&A [(size_t)(m0 + row) * K + kt + kc]);
            *(uint4*)(&Bs[row * 32 + kc]) =
                *(const uint4*)(&Bt[(size_t)(n0 + row) * K + kt + kc]);
        }
        __syncthreads();

        bf16x8 af[4], bfv[4];
        #pragma unroll
        for (int i = 0; i < 4; ++i)
            af[i]  = *(const bf16x8*)(&As[(wm + i * 16 + l16) * 32 + quad * 8]);
        #pragma unroll
        for (int j = 0; j < 4; ++j)
            bfv[j] = *(const bf16x8*)(&Bs[(wn + j * 16 + l16) * 32 + quad * 8]);
        #pragma unroll
        for (int i = 0; i < 4; ++i)
            #pragma unroll
            for (int j = 0; j < 4; ++j)
                acc[i][j] = mfma16(af[i], bfv[j], acc[i][j]);
        __syncthreads();
    }

    // C/D layout: col = lane&15, row = quad*4 + reg  [m89/m91]
    #pragma unroll
    for (int i = 0; i < 4; ++i) {
        #pragma unroll
        for (int j = 0; j < 4; ++j) {
            int col = n0 + wn + j * 16 + l16;
            #pragma unroll
            for (int r = 0; r < 4; ++r) {
                int row = m0 + wm + i * 16 + quad * 4 + r;
                if (MODE == 0) {
                    Cp[(size_t)row * N + col] = acc[i][j][r];
                } else {
                    __hip_bfloat16 v = __float2bfloat16(acc[i][j][r]);
                    int bb = row >> 11, s = row & 2047;
                    int d  = col & 127;
                    if (col < 4096) {
                        int h = col >> 7;
                        Qr[(((size_t)bb * 32 + h) * 2048 + s) * 128 + d] = v;
                    } else if (col < 5120) {
                        int kvh = (col - 4096) >> 7;
                        Kr[(((size_t)bb * 8 + kvh) * 2048 + s) * 128 + d] = v;
                    } else {
                        int kvh = (col - 5120) >> 7;
                        Vv[(((size_t)bb * 8 + kvh) * 2048 + s) * 128 + d] = v;
                    }
                }
            }
        }
    }
}

// ---------------------------------------------------------------------------
// In-place RoPE on x[row][128].  s = row & 2047, b = row >> bshift.
// pos = positions[b*2048 + s].  ang = pos * 10000^(-d/64).
// ---------------------------------------------------------------------------
__global__ __launch_bounds__(256)
void rope_kernel(__hip_bfloat16* __restrict__ x,
                 const int* __restrict__ positions, int nrows, int bshift) {
    int gid = blockIdx.x * 256 + threadIdx.x;
    if (gid >= nrows * 64) return;
    int row = gid >> 6, d = gid & 63;
    int s = row & 2047;
    int b = row >> bshift;
    float p = (float)positions[(b << 11) + s];
    // ln(10000)/64 = 0.14391156831212787
    float ang = p * expf(-0.14391156831212787f * (float)d);
    float sn, cs;
    sincosf(ang, &sn, &cs);
    __hip_bfloat16* ptr = x + (size_t)row * 128;
    float x1 = __bfloat162float(ptr[d]);
    float x2 = __bfloat162float(ptr[d + 64]);
    ptr[d]      = __float2bfloat16(x1 * cs - x2 * sn);
    ptr[d + 64] = __float2bfloat16(x2 * cs + x1 * sn);
}

// ---------------------------------------------------------------------------
// Flash attention, causal, GQA (kv = h>>2).  One wave per block.
// Q tile = 32 rows, key blocks of 32.  Qr[b][h][s][d], Kr[b][kv][s][d],
// Vt[b][kv][d][s], out Ao[b][s][h*128+d] (bf16).
// grid = (S/32, NH, B), block = 64.
// ---------------------------------------------------------------------------
__global__ __launch_bounds__(64)
void attn_kernel(const __hip_bfloat16* __restrict__ Qr,
                 const __hip_bfloat16* __restrict__ Kr,
                 const __hip_bfloat16* __restrict__ Vt,
                 __hip_bfloat16* __restrict__ Ao) {
    __shared__ __align__(16) __hip_bfloat16 P_lds[32 * 32];

    const int lane = threadIdx.x;
    const int quad = lane >> 4, l16 = lane & 15;
    const int q0 = blockIdx.x * 32;
    const int h  = blockIdx.y;
    const int b  = blockIdx.z;
    const int kv = h >> 2;

    const __hip_bfloat16* Qb = Qr + ((size_t)b * 32 + h)  * 2048 * 128;
    const __hip_bfloat16* Kb = Kr + ((size_t)b * 8  + kv) * 2048 * 128;
    const __hip_bfloat16* Vb = Vt + ((size_t)b * 8  + kv) * 128 * 2048;

    // Q fragments resident: A-layout m=lane&15, k=quad*8+j
    bf16x8 qf[2][4];
    #pragma unroll
    for (int i = 0; i < 2; ++i)
        #pragma unroll
        for (int kc = 0; kc < 4; ++kc)
            qf[i][kc] = *(const bf16x8*)(
                &Qb[(size_t)(q0 + i * 16 + l16) * 128 + kc * 32 + quad * 8]);

    float m_i[2][4], l_i[2][4];
    #pragma unroll
    for (int i = 0; i < 2; ++i)
        #pragma unroll
        for (int r = 0; r < 4; ++r) { m_i[i][r] = -1e30f; l_i[i][r] = 0.0f; }
    floatx4 o[2][8] = {};

    const float scale = 0.08838834764831845f;  // 1/sqrt(128)

    for (int ks = 0; ks <= q0; ks += 32) {
        // ---- S = Q K^T  (C layout: row(q)=quad*4+r, col(key)=l16) ----
        floatx4 sacc[2][2] = {};
        #pragma unroll
        for (int j = 0; j < 2; ++j) {
            #pragma unroll
            for (int kc = 0; kc < 4; ++kc) {
                bf16x8 kf = *(const bf16x8*)(
                    &Kb[(size_t)(ks + j * 16 + l16) * 128 + kc * 32 + quad * 8]);
                #pragma unroll
                for (int i = 0; i < 2; ++i)
                    sacc[i][j] = mfma16(qf[i][kc], kf, sacc[i][j]);
            }
        }

        // ---- online softmax (row = quad*4+r, 16 cols live in l16 lanes of
        //      the same quad group; xor-shuffles 1/2/4/8 stay in-group) ----
        float pv[2][2][4], alpha[2][4];
        #pragma unroll
        for (int i = 0; i < 2; ++i) {
            #pragma unroll
            for (int r = 0; r < 4; ++r) {
                int row = q0 + i * 16 + quad * 4 + r;
                float s0 = sacc[i][0][r] * scale;
                float s1 = sacc[i][1][r] * scale;
                if (ks + l16 > row)      s0 = -1e30f;
                if (ks + 16 + l16 > row) s1 = -1e30f;
                float mx = fmaxf(s0, s1);
                #pragma unroll
                for (int off = 1; off < 16; off <<= 1)
                    mx = fmaxf(mx, __shfl_xor(mx, off, 64));
                float mnew = fmaxf(m_i[i][r], mx);
                float a  = __expf(m_i[i][r] - mnew);
                float p0 = __expf(s0 - mnew);
                float p1 = __expf(s1 - mnew);
                float rs = p0 + p1;
                #pragma unroll
                for (int off = 1; off < 16; off <<= 1)
                    rs += __shfl_xor(rs, off, 64);
                l_i[i][r] = l_i[i][r] * a + rs;
                m_i[i][r] = mnew;
                alpha[i][r] = a;
                pv[i][0][r] = p0;
                pv[i][1][r] = p1;
            }
        }

        #pragma unroll
        for (int i = 0; i < 2; ++i)
            #pragma unroll
            for (int dn = 0; dn < 8; ++dn)
                #pragma unroll
                for (int r = 0; r < 4; ++r)
                    o[i][dn][r] *= alpha[i][r];

        // ---- P: C-layout -> LDS -> A-layout ----
        #pragma unroll
        for (int i = 0; i < 2; ++i)
            #pragma unroll
            for (int j = 0; j < 2; ++j)
                #pragma unroll
                for (int r = 0; r < 4; ++r)
                    P_lds[(i * 16 + quad * 4 + r) * 32 + j * 16 + l16] =
                        __float2bfloat16(pv[i][j][r]);
        __syncthreads();

        bf16x8 pf[2];
        #pragma unroll
        for (int i = 0; i < 2; ++i)
            pf[i] = *(const bf16x8*)(&P_lds[(i * 16 + l16) * 32 + quad * 8]);

        // ---- O += P V  (B-frag from Vt: n=d=l16, k=key contiguous) ----
        #pragma unroll
        for (int dn = 0; dn < 8; ++dn) {
            bf16x8 vf = *(const bf16x8*)(
                &Vb[(size_t)(dn * 16 + l16) * 2048 + ks + quad * 8]);
            #pragma unroll
            for (int i = 0; i < 2; ++i)
                o[i][dn] = mfma16(pf[i], vf, o[i][dn]);
        }
        __syncthreads();
    }

    #pragma unroll
    for (int i = 0; i < 2; ++i) {
        #pragma unroll
        for (int r = 0; r < 4; ++r) {
            float inv = 1.0f / l_i[i][r];
            int row = q0 + i * 16 + quad * 4 + r;
            size_t base = ((size_t)b * 2048 + row) * 4096 + (size_t)h * 128;
            #pragma unroll
            for (int dn = 0; dn < 8; ++dn)
                Ao[base + dn * 16 + l16] = __float2bfloat16(o[i][dn][r] * inv);
        }
    }
}

// ---------------------------------------------------------------------------
extern "C" void kernel_launch(void* const* d_in, const int* in_sizes, int n_in,
                              void* d_out, int out_size, void* d_ws, size_t ws_size,
                              hipStream_t stream) {
    // inputs (fp32 per reference): 0=positions(int32), 1=hidden (2*2048*4096),
    // 2=w_qkv (4096*6144), 3=w_o (4096*4096).  Output: fp32, 2*2048*4096.
    const int*   positions = (const int*)d_in[0];
    const float* hidden    = (const float*)d_in[1];
    const float* wqkv      = (const float*)d_in[2];
    const float* wo        = (const float*)d_in[3];
    float* out = (float*)d_out;

    // workspace (bf16 elems). Aliases: Ao <- WqkvT (dead after GEMM1),
    //                                  Vt <- Hb   (dead after GEMM1).
    __hip_bfloat16* WqkvT = (__hip_bfloat16*)d_ws;        // 6144*4096 = 25165824
    __hip_bfloat16* WoT   = WqkvT + 25165824;             // 4096*4096 = 16777216
    __hip_bfloat16* Hb    = WoT   + 16777216;             // 4096*4096 = 16777216
    __hip_bfloat16* Qr    = Hb    + 16777216;             // 2*32*2048*128 = 16777216
    __hip_bfloat16* Kr    = Qr    + 16777216;             // 2*8*2048*128  = 4194304
    __hip_bfloat16* Vv    = Kr    + 4194304;              // 4194304
    __hip_bfloat16* Ao    = WqkvT;                        // alias (16777216)
    __hip_bfloat16* Vt    = Hb;                           // alias (4194304)
    // total = 83,886,080 elems = 160 MiB

    // 1) converts / weight transposes
    convert_kernel<<<16777216 / 1024, 256, 0, stream>>>(hidden, Hb, 16777216);
    transpose_f32_bf16_kernel<<<dim3(6144 / 64, 4096 / 64), 256, 0, stream>>>(
        wqkv, WqkvT, 4096, 6144);
    transpose_f32_bf16_kernel<<<dim3(4096 / 64, 4096 / 64), 256, 0, stream>>>(
        wo, WoT, 4096, 4096);

    // 2) QKV projection with scatter epilogue
    gemm_bt_kernel<1><<<dim3(6144 / 128, 4096 / 128), 256, 0, stream>>>(
        Hb, WqkvT, nullptr, Qr, Kr, Vv, 4096, 6144, 4096);

    // 3) RoPE in place (Q rows: b = row>>16; K rows: b = row>>14)
    rope_kernel<<<(131072 * 64) / 256, 256, 0, stream>>>(Qr, positions, 131072, 16);
    rope_kernel<<<(32768  * 64) / 256, 256, 0, stream>>>(Kr, positions, 32768, 14);

    // 4) V transpose: Vv[b*kv][2048][128] -> Vt[b*kv][128][2048]
    transpose_bf16_kernel<<<dim3(128 / 64, 2048 / 64, 16), 256, 0, stream>>>(
        Vv, Vt, 2048, 128);

    // 5) flash attention -> Ao[b][s][h*128+d]
    attn_kernel<<<dim3(2048 / 32, 32, 2), 64, 0, stream>>>(Qr, Kr, Vt, Ao);

    // 6) output projection -> d_out (fp32)
    gemm_bt_kernel<0><<<dim3(4096 / 128, 4096 / 128), 256, 0, stream>>>(
        Ao, WoT, out, nullptr, nullptr, nullptr, 4096, 4096, 4096);
}

// Round 3
// 1226.432 us; speedup vs baseline: 1.0391x; 1.0391x over previous
//
#include <hip/hip_runtime.h>
#include <hip/hip_bf16.h>
#include <math.h>

// B=2, S=2048, H=4096, NH=32, NKV=8, HD=128, Q_SIZE=4096, KV_SIZE=1024, N_qkv=6144
// fp32 inputs/outputs; bf16 MFMA pipeline with fp32 accumulation.

typedef __attribute__((ext_vector_type(8))) __bf16 bf16x8;
typedef __attribute__((ext_vector_type(4))) float floatx4;

__device__ __forceinline__ floatx4 mfma16(bf16x8 a, bf16x8 b, floatx4 c) {
    return __builtin_amdgcn_mfma_f32_16x16x32_bf16(a, b, c, 0, 0, 0);
}

// async global->LDS, 16B per lane. dst must be wave-uniform base; HW writes
// lane i at dst + i*16B.  [m97: global_load_lds_dwordx4]
__device__ __forceinline__ void load_lds16(const __hip_bfloat16* g,
                                           __hip_bfloat16* lds_base_uniform) {
    __builtin_amdgcn_global_load_lds(
        (const __attribute__((address_space(1))) unsigned int*)g,
        (__attribute__((address_space(3))) unsigned int*)lds_base_uniform,
        16, 0, 0);
}

// ---------------------------------------------------------------------------
// fp32 -> bf16 elementwise convert. n % 1024 == 0.
// ---------------------------------------------------------------------------
__global__ __launch_bounds__(256)
void convert_kernel(const float* __restrict__ in, __hip_bfloat16* __restrict__ out,
                    int n) {
    int i = (blockIdx.x * 256 + threadIdx.x) * 4;
    if (i >= n) return;
    float4 v = *(const float4*)(in + i);
    union { __hip_bfloat16 h[4]; uint2 u; } pk;
    pk.h[0] = __float2bfloat16(v.x);
    pk.h[1] = __float2bfloat16(v.y);
    pk.h[2] = __float2bfloat16(v.z);
    pk.h[3] = __float2bfloat16(v.w);
    *(uint2*)(out + i) = pk.u;
}

// ---------------------------------------------------------------------------
// fp32 in[r][c] -> bf16 out[c][r] transpose (weights).
// ---------------------------------------------------------------------------
__global__ __launch_bounds__(256)
void transpose_f32_bf16_kernel(const float* __restrict__ in,
                               __hip_bfloat16* __restrict__ out, int R, int C) {
    __shared__ __hip_bfloat16 tile[64][65];
    const int r0 = blockIdx.y * 64, c0 = blockIdx.x * 64;
    const int t = threadIdx.x;
    #pragma unroll
    for (int i = 0; i < 16; ++i) {
        int idx = t + 256 * i;
        int rl = idx >> 6, cl = idx & 63;
        tile[rl][cl] = __float2bfloat16(in[(size_t)(r0 + rl) * C + (c0 + cl)]);
    }
    __syncthreads();
    #pragma unroll
    for (int i = 0; i < 16; ++i) {
        int idx = t + 256 * i;
        int cl = idx >> 6, rl = idx & 63;
        out[(size_t)(c0 + cl) * R + (r0 + rl)] = tile[rl][cl];
    }
}

// ---------------------------------------------------------------------------
// bf16 batched transpose: in[b][r][c] -> out[b][c][r].
// ---------------------------------------------------------------------------
__global__ __launch_bounds__(256)
void transpose_bf16_kernel(const __hip_bfloat16* __restrict__ in,
                           __hip_bfloat16* __restrict__ out, int R, int C) {
    __shared__ __hip_bfloat16 tile[64][65];
    const int bz = blockIdx.z;
    const __hip_bfloat16* inb  = in  + (size_t)bz * R * C;
    __hip_bfloat16*       outb = out + (size_t)bz * R * C;
    const int r0 = blockIdx.y * 64, c0 = blockIdx.x * 64;
    const int t = threadIdx.x;
    #pragma unroll
    for (int i = 0; i < 16; ++i) {
        int idx = t + 256 * i;
        int rl = idx >> 6, cl = idx & 63;
        tile[rl][cl] = inb[(size_t)(r0 + rl) * C + (c0 + cl)];
    }
    __syncthreads();
    #pragma unroll
    for (int i = 0; i < 16; ++i) {
        int idx = t + 256 * i;
        int cl = idx >> 6, rl = idx & 63;
        outb[(size_t)(c0 + cl) * R + (r0 + rl)] = tile[rl][cl];
    }
}

// ---------------------------------------------------------------------------
// bf16 GEMM: C[M,N] = A[M,K] * Bt[N,K]^T.  128x128 tile, BK=32, 4 waves.
// Staging via global_load_lds width=16 (m97).  LDS element offset = idx*8,
// so per-wave dest base = (wave*64 + 256*i)*8 — wave-uniform, lane*16B apart.
// MODE 0: fp32 store to Cp.  MODE 1: QKV scatter (bf16).
// ---------------------------------------------------------------------------
template <int MODE>
__global__ __launch_bounds__(256)
void gemm_bt_kernel(const __hip_bfloat16* __restrict__ A,
                    const __hip_bfloat16* __restrict__ Bt,
                    float* __restrict__ Cp,
                    __hip_bfloat16* __restrict__ Qr,
                    __hip_bfloat16* __restrict__ Kr,
                    __hip_bfloat16* __restrict__ Vv,
                    int M, int N, int K) {
    __shared__ __align__(16) __hip_bfloat16 As[128 * 32];
    __shared__ __align__(16) __hip_bfloat16 Bs[128 * 32];

    const int m0 = blockIdx.y * 128, n0 = blockIdx.x * 128;
    const int tid  = threadIdx.x;
    const int wave = tid >> 6, lane = tid & 63;
    const int quad = lane >> 4, l16 = lane & 15;
    const int wm = (wave >> 1) * 64, wn = (wave & 1) * 64;

    floatx4 acc[4][4] = {};

    for (int kt = 0; kt < K; kt += 32) {
        #pragma unroll
        for (int i = 0; i < 2; ++i) {
            int idx = tid + 256 * i;
            int row = idx >> 2;
            int kc  = (idx & 3) << 3;
            __hip_bfloat16* dstA = &As[(size_t)(wave * 64 + 256 * i) * 8];
            __hip_bfloat16* dstB = &Bs[(size_t)(wave * 64 + 256 * i) * 8];
            load_lds16(&A [(size_t)(m0 + row) * K + kt + kc], dstA);
            load_lds16(&Bt[(size_t)(n0 + row) * K + kt + kc], dstB);
        }
        __syncthreads();

        bf16x8 af[4], bfv[4];
        #pragma unroll
        for (int i = 0; i < 4; ++i)
            af[i]  = *(const bf16x8*)(&As[(wm + i * 16 + l16) * 32 + quad * 8]);
        #pragma unroll
        for (int j = 0; j < 4; ++j)
            bfv[j] = *(const bf16x8*)(&Bs[(wn + j * 16 + l16) * 32 + quad * 8]);
        #pragma unroll
        for (int i = 0; i < 4; ++i)
            #pragma unroll
            for (int j = 0; j < 4; ++j)
                acc[i][j] = mfma16(af[i], bfv[j], acc[i][j]);
        __syncthreads();
    }

    // C/D layout: col = lane&15, row = quad*4 + reg  [m89/m91]
    #pragma unroll
    for (int i = 0; i < 4; ++i) {
        #pragma unroll
        for (int j = 0; j < 4; ++j) {
            int col = n0 + wn + j * 16 + l16;
            #pragma unroll
            for (int r = 0; r < 4; ++r) {
                int row = m0 + wm + i * 16 + quad * 4 + r;
                if (MODE == 0) {
                    Cp[(size_t)row * N + col] = acc[i][j][r];
                } else {
                    __hip_bfloat16 v = __float2bfloat16(acc[i][j][r]);
                    int bb = row >> 11, s = row & 2047;
                    int d  = col & 127;
                    if (col < 4096) {
                        int h = col >> 7;
                        Qr[(((size_t)bb * 32 + h) * 2048 + s) * 128 + d] = v;
                    } else if (col < 5120) {
                        int kvh = (col - 4096) >> 7;
                        Kr[(((size_t)bb * 8 + kvh) * 2048 + s) * 128 + d] = v;
                    } else {
                        int kvh = (col - 5120) >> 7;
                        Vv[(((size_t)bb * 8 + kvh) * 2048 + s) * 128 + d] = v;
                    }
                }
            }
        }
    }
}

// ---------------------------------------------------------------------------
// In-place RoPE on x[row][128].  s = row & 2047, b = row >> bshift.
// ---------------------------------------------------------------------------
__global__ __launch_bounds__(256)
void rope_kernel(__hip_bfloat16* __restrict__ x,
                 const int* __restrict__ positions, int nrows, int bshift) {
    int gid = blockIdx.x * 256 + threadIdx.x;
    if (gid >= nrows * 64) return;
    int row = gid >> 6, d = gid & 63;
    int s = row & 2047;
    int b = row >> bshift;
    float p = (float)positions[(b << 11) + s];
    float ang = p * expf(-0.14391156831212787f * (float)d);  // ln(1e4)/64
    float sn, cs;
    sincosf(ang, &sn, &cs);
    __hip_bfloat16* ptr = x + (size_t)row * 128;
    float x1 = __bfloat162float(ptr[d]);
    float x2 = __bfloat162float(ptr[d + 64]);
    ptr[d]      = __float2bfloat16(x1 * cs - x2 * sn);
    ptr[d + 64] = __float2bfloat16(x2 * cs + x1 * sn);
}

// ---------------------------------------------------------------------------
// Flash attention v2, causal, GQA.  256 threads = 4 waves; Q-tile = 128 rows
// (32/wave); K/V 32-key blocks staged in padded LDS (shared by the 4 waves).
// Padding: Ks stride 136 (l16*68 dwords -> 2-way, free), Vs stride 36,
// P stride 40 (per-wave buffer).  blockIdx.x reversed: heavy causal blocks
// dispatch first.
// grid = (S/128, NH, B), block = 256.
// ---------------------------------------------------------------------------
__global__ __launch_bounds__(256)
void attn_kernel(const __hip_bfloat16* __restrict__ Qr,
                 const __hip_bfloat16* __restrict__ Kr,
                 const __hip_bfloat16* __restrict__ Vt,
                 __hip_bfloat16* __restrict__ Ao) {
    __shared__ __align__(16) __hip_bfloat16 Ks[32 * 136];
    __shared__ __align__(16) __hip_bfloat16 Vs[128 * 36];
    __shared__ __align__(16) __hip_bfloat16 Pl[4][32 * 40];

    const int tid  = threadIdx.x;
    const int wave = tid >> 6, lane = tid & 63;
    const int quad = lane >> 4, l16 = lane & 15;
    const int qb = (gridDim.x - 1) - blockIdx.x;      // heavy blocks first
    const int q0 = qb * 128;
    const int qr0 = q0 + wave * 32;                   // this wave's 32 rows
    const int h  = blockIdx.y;
    const int b  = blockIdx.z;
    const int kv = h >> 2;

    const __hip_bfloat16* Qb = Qr + ((size_t)b * 32 + h)  * 2048 * 128;
    const __hip_bfloat16* Kb = Kr + ((size_t)b * 8  + kv) * 2048 * 128;
    const __hip_bfloat16* Vb = Vt + ((size_t)b * 8  + kv) * 128 * 2048;

    // Q fragments resident: A-layout m=lane&15, k=quad*8+j
    bf16x8 qf[2][4];
    #pragma unroll
    for (int i = 0; i < 2; ++i)
        #pragma unroll
        for (int kc = 0; kc < 4; ++kc)
            qf[i][kc] = *(const bf16x8*)(
                &Qb[(size_t)(qr0 + i * 16 + l16) * 128 + kc * 32 + quad * 8]);

    float m_i[2][4], l_i[2][4];
    #pragma unroll
    for (int i = 0; i < 2; ++i)
        #pragma unroll
        for (int r = 0; r < 4; ++r) { m_i[i][r] = -1e30f; l_i[i][r] = 0.0f; }
    floatx4 o[2][8] = {};

    const float scale = 0.08838834764831845f;  // 1/sqrt(128)
    const int kmax = q0 + 127;                 // block-level causal max row

    for (int ks = 0; ks <= kmax; ks += 32) {
        // ---- cooperative staging: K 32x128 -> Ks[32][136] ----
        #pragma unroll
        for (int p = 0; p < 2; ++p) {
            int idx = tid + 256 * p;
            int krow = idx >> 4, kcol = (idx & 15) << 3;
            *(uint4*)(&Ks[krow * 136 + kcol]) =
                *(const uint4*)(&Kb[(size_t)(ks + krow) * 128 + kcol]);
        }
        // ---- V 128x32 (Vt rows = d) -> Vs[128][36] ----
        #pragma unroll
        for (int p = 0; p < 2; ++p) {
            int idx = tid + 256 * p;
            int d = idx >> 2, koff = (idx & 3) << 3;
            *(uint4*)(&Vs[d * 36 + koff]) =
                *(const uint4*)(&Vb[(size_t)d * 2048 + ks + koff]);
        }
        __syncthreads();

        if (ks <= qr0 + 31) {   // wave-uniform causal guard
            // ---- S = Q K^T ----
            floatx4 sacc[2][2] = {};
            #pragma unroll
            for (int j = 0; j < 2; ++j) {
                #pragma unroll
                for (int kc = 0; kc < 4; ++kc) {
                    bf16x8 kf = *(const bf16x8*)(
                        &Ks[(j * 16 + l16) * 136 + kc * 32 + quad * 8]);
                    #pragma unroll
                    for (int i = 0; i < 2; ++i)
                        sacc[i][j] = mfma16(qf[i][kc], kf, sacc[i][j]);
                }
            }

            // ---- online softmax ----
            float pv[2][2][4], alpha[2][4];
            #pragma unroll
            for (int i = 0; i < 2; ++i) {
                #pragma unroll
                for (int r = 0; r < 4; ++r) {
                    int row = qr0 + i * 16 + quad * 4 + r;
                    float s0 = sacc[i][0][r] * scale;
                    float s1 = sacc[i][1][r] * scale;
                    if (ks + l16 > row)      s0 = -1e30f;
                    if (ks + 16 + l16 > row) s1 = -1e30f;
                    float mx = fmaxf(s0, s1);
                    #pragma unroll
                    for (int off = 1; off < 16; off <<= 1)
                        mx = fmaxf(mx, __shfl_xor(mx, off, 64));
                    float mnew = fmaxf(m_i[i][r], mx);
                    float a  = __expf(m_i[i][r] - mnew);
                    float p0 = __expf(s0 - mnew);
                    float p1 = __expf(s1 - mnew);
                    float rs = p0 + p1;
                    #pragma unroll
                    for (int off = 1; off < 16; off <<= 1)
                        rs += __shfl_xor(rs, off, 64);
                    l_i[i][r] = l_i[i][r] * a + rs;
                    m_i[i][r] = mnew;
                    alpha[i][r] = a;
                    pv[i][0][r] = p0;
                    pv[i][1][r] = p1;
                }
            }

            #pragma unroll
            for (int i = 0; i < 2; ++i)
                #pragma unroll
                for (int dn = 0; dn < 8; ++dn)
                    #pragma unroll
                    for (int r = 0; r < 4; ++r)
                        o[i][dn][r] *= alpha[i][r];

            // ---- P: C-layout -> per-wave LDS -> A-layout ----
            #pragma unroll
            for (int i = 0; i < 2; ++i)
                #pragma unroll
                for (int j = 0; j < 2; ++j)
                    #pragma unroll
                    for (int r = 0; r < 4; ++r)
                        Pl[wave][(i * 16 + quad * 4 + r) * 40 + j * 16 + l16] =
                            __float2bfloat16(pv[i][j][r]);

            bf16x8 pf[2];
            #pragma unroll
            for (int i = 0; i < 2; ++i)
                pf[i] = *(const bf16x8*)(&Pl[wave][(i * 16 + l16) * 40 + quad * 8]);

            // ---- O += P V ----
            #pragma unroll
            for (int dn = 0; dn < 8; ++dn) {
                bf16x8 vf = *(const bf16x8*)(
                    &Vs[(dn * 16 + l16) * 36 + quad * 8]);
                #pragma unroll
                for (int i = 0; i < 2; ++i)
                    o[i][dn] = mfma16(pf[i], vf, o[i][dn]);
            }
        }
        __syncthreads();
    }

    // ---- write Ao[b][s][h*128+d] ----
    #pragma unroll
    for (int i = 0; i < 2; ++i) {
        #pragma unroll
        for (int r = 0; r < 4; ++r) {
            float inv = 1.0f / l_i[i][r];
            int row = qr0 + i * 16 + quad * 4 + r;
            size_t base = ((size_t)b * 2048 + row) * 4096 + (size_t)h * 128;
            #pragma unroll
            for (int dn = 0; dn < 8; ++dn)
                Ao[base + dn * 16 + l16] = __float2bfloat16(o[i][dn][r] * inv);
        }
    }
}

// ---------------------------------------------------------------------------
extern "C" void kernel_launch(void* const* d_in, const int* in_sizes, int n_in,
                              void* d_out, int out_size, void* d_ws, size_t ws_size,
                              hipStream_t stream) {
    const int*   positions = (const int*)d_in[0];
    const float* hidden    = (const float*)d_in[1];
    const float* wqkv      = (const float*)d_in[2];
    const float* wo        = (const float*)d_in[3];
    float* out = (float*)d_out;

    __hip_bfloat16* WqkvT = (__hip_bfloat16*)d_ws;        // 25165824
    __hip_bfloat16* WoT   = WqkvT + 25165824;             // 16777216
    __hip_bfloat16* Hb    = WoT   + 16777216;             // 16777216
    __hip_bfloat16* Qr    = Hb    + 16777216;             // 16777216
    __hip_bfloat16* Kr    = Qr    + 16777216;             // 4194304
    __hip_bfloat16* Vv    = Kr    + 4194304;              // 4194304
    __hip_bfloat16* Ao    = WqkvT;                        // alias (dead after GEMM1)
    __hip_bfloat16* Vt    = Hb;                           // alias (dead after GEMM1)
    // total 160 MiB

    convert_kernel<<<16777216 / 1024, 256, 0, stream>>>(hidden, Hb, 16777216);
    transpose_f32_bf16_kernel<<<dim3(6144 / 64, 4096 / 64), 256, 0, stream>>>(
        wqkv, WqkvT, 4096, 6144);
    transpose_f32_bf16_kernel<<<dim3(4096 / 64, 4096 / 64), 256, 0, stream>>>(
        wo, WoT, 4096, 4096);

    gemm_bt_kernel<1><<<dim3(6144 / 128, 4096 / 128), 256, 0, stream>>>(
        Hb, WqkvT, nullptr, Qr, Kr, Vv, 4096, 6144, 4096);

    rope_kernel<<<(131072 * 64) / 256, 256, 0, stream>>>(Qr, positions, 131072, 16);
    rope_kernel<<<(32768  * 64) / 256, 256, 0, stream>>>(Kr, positions, 32768, 14);

    transpose_bf16_kernel<<<dim3(128 / 64, 2048 / 64, 16), 256, 0, stream>>>(
        Vv, Vt, 2048, 128);

    attn_kernel<<<dim3(2048 / 128, 32, 2), 256, 0, stream>>>(Qr, Kr, Vt, Ao);

    gemm_bt_kernel<0><<<dim3(4096 / 128, 4096 / 128), 256, 0, stream>>>(
        Ao, WoT, out, nullptr, nullptr, nullptr, 4096, 4096, 4096);
}